// Round 2
// baseline (364.941 us; speedup 1.0000x reference)
//
#include <hip/hip_runtime.h>

typedef unsigned short u16;
typedef __attribute__((ext_vector_type(8)))  short bf16x8;
typedef __attribute__((ext_vector_type(16))) float f32x16;

#define NROWS 131072
#define NMOL  2048
#define CIN   128
#define HDIM  1024
#define BM    64
#define EMBSTRIDE 1152   // 9*128

#define KT1 (CIN  / 16)   // 8
#define KT2 (HDIM / 16)   // 64
#define NT  (HDIM / 32)   // 32

// ---------- helpers ----------
__device__ __forceinline__ u16 f2bf(float f) {
    union { float f; unsigned u; } v; v.f = f;
    unsigned u = v.u;
    u += 0x7FFFu + ((u >> 16) & 1u);   // round-to-nearest-even
    return (u16)(u >> 16);
}

__device__ __forceinline__ float silu_f(float v) {
    float e = __expf(-v);
    return v * __builtin_amdgcn_rcpf(1.0f + e);
}

__device__ __forceinline__ f32x16 mfma32(bf16x8 a, bf16x8 b, f32x16 c) {
    return __builtin_amdgcn_mfma_f32_32x32x16_bf16(a, b, c, 0, 0, 0);
}

// ---------- pre-pass: pack W (K x N fp32 row-major) into bf16 32x32x16 B-fragments ----------
// frag id = kt*NT + nt (kt slow-streams). lane l, elem j -> W[kt*16 + (l>>5)*8 + j][nt*32 + (l&31)]
__global__ void pack_w32(const float* __restrict__ W, u16* __restrict__ dst, int K, int N) {
    int tid  = blockIdx.x * blockDim.x + threadIdx.x;
    int lane = tid & 63;
    int frag = tid >> 6;
    int NTl = N >> 5;
    int KTl = K >> 4;
    if (frag >= KTl * NTl) return;
    int kt = frag / NTl;
    int nt = frag - kt * NTl;
    int col  = (nt << 5) + (lane & 31);
    int krow = (kt << 4) + ((lane >> 5) << 3);
    __align__(16) u16 tmp[8];
    #pragma unroll
    for (int j = 0; j < 8; ++j) tmp[j] = f2bf(W[(size_t)(krow + j) * N + col]);
    *reinterpret_cast<uint4*>(dst + (size_t)tid * 8) = *reinterpret_cast<uint4*>(tmp);
}

// ---------- fused MLP ----------
__global__ __launch_bounds__(512, 2) void fused_mlp(
    const float* __restrict__ emb,
    const u16*  __restrict__ w1f,
    const u16*  __restrict__ w2f,
    const float* __restrict__ b1,
    const float* __restrict__ b2,
    const float* __restrict__ w3,
    const float* __restrict__ b3,
    float* __restrict__ node_e)
{
    __shared__ u16  x_lds[BM][CIN + 8];      // 64 x 136 bf16 : 17.4 KB (stride 272B, 16B-aligned)
    __shared__ u16  h1_lds[BM][HDIM + 8];    // 64 x 1032 bf16: 132 KB (stride 2064B, 16B-aligned)
    __shared__ float e_red[8][BM];           // 2 KB

    const int tid  = threadIdx.x;
    const int lane = tid & 63;
    const int w    = tid >> 6;               // wave 0..7; covers cols [w*128, w*128+128)
    const int l31  = lane & 31;
    const int lhi  = lane >> 5;              // 0/1
    const int row0 = blockIdx.x * BM;

    // ---- phase 0: stage x tile as bf16 ----
    {
        int r   = tid >> 3;                  // 0..63
        int seg = tid & 7;                   // 8 segs of 16 floats
        const float4* s4 = reinterpret_cast<const float4*>(
            emb + (size_t)(row0 + r) * EMBSTRIDE + seg * 16);
        __align__(16) u16 u[16];
        #pragma unroll
        for (int i = 0; i < 4; ++i) {
            float4 f = s4[i];
            u[i*4+0] = f2bf(f.x); u[i*4+1] = f2bf(f.y);
            u[i*4+2] = f2bf(f.z); u[i*4+3] = f2bf(f.w);
        }
        uint4* d = reinterpret_cast<uint4*>(&x_lds[r][seg * 16]);
        d[0] = reinterpret_cast<uint4*>(u)[0];
        d[1] = reinterpret_cast<uint4*>(u)[1];
    }

    // B-fragment loaders (from packed streams, frag = kt*NT + nt, nt = w*4 + nti)
    auto LDB1 = [&](int kt, bf16x8* b) {
        #pragma unroll
        for (int nti = 0; nti < 4; ++nti)
            b[nti] = *reinterpret_cast<const bf16x8*>(
                w1f + (((size_t)kt * NT + w * 4 + nti) * 64 + lane) * 8);
    };
    auto LDB2 = [&](int kt, bf16x8* b) {
        #pragma unroll
        for (int nti = 0; nti < 4; ++nti)
            b[nti] = *reinterpret_cast<const bf16x8*>(
                w2f + (((size_t)kt * NT + w * 4 + nti) * 64 + lane) * 8);
    };

    // prefetch GEMM1 B(kt=0) before the staging barrier (independent of LDS)
    bf16x8 bC[4], bN[4];
    LDB1(0, bC);
    __syncthreads();

    // ---- phase 1: h1 = silu(x @ W1 + b1) ----
    {
        f32x16 acc1[2][4];
        #pragma unroll
        for (int mt = 0; mt < 2; ++mt)
            #pragma unroll
            for (int nti = 0; nti < 4; ++nti)
                #pragma unroll
                for (int r = 0; r < 16; ++r) acc1[mt][nti][r] = 0.0f;

        #pragma unroll
        for (int kt = 0; kt < KT1; ++kt) {
            if (kt + 1 < KT1) LDB1(kt + 1, bN);
            bf16x8 a[2];
            #pragma unroll
            for (int mt = 0; mt < 2; ++mt)
                a[mt] = *reinterpret_cast<const bf16x8*>(
                    &x_lds[mt*32 + l31][kt*16 + (lhi << 3)]);
            #pragma unroll
            for (int nti = 0; nti < 4; ++nti)
                #pragma unroll
                for (int mt = 0; mt < 2; ++mt)
                    acc1[mt][nti] = mfma32(a[mt], bC[nti], acc1[mt][nti]);
            if (kt + 1 < KT1) {
                #pragma unroll
                for (int i = 0; i < 4; ++i) bC[i] = bN[i];
            }
        }

        // epilogue: silu -> bf16 -> h1_lds  (C/D: col=lane&31, row=(r&3)+8*(r>>2)+4*lhi)
        #pragma unroll
        for (int nti = 0; nti < 4; ++nti) {
            int col = w*128 + nti*32 + l31;
            float bias = b1[col];
            #pragma unroll
            for (int mt = 0; mt < 2; ++mt)
                #pragma unroll
                for (int r = 0; r < 16; ++r) {
                    int row = mt*32 + (r & 3) + 8*(r >> 2) + 4*lhi;
                    h1_lds[row][col] = f2bf(silu_f(acc1[mt][nti][r] + bias));
                }
        }
    }

    // prefetch GEMM2 B(0), B(1) before the phase barrier (independent of h1)
    LDB2(0, bC);
    LDB2(1, bN);
    __syncthreads();

    // ---- phase 2: h2 = silu(h1 @ W2 + b2), fold (h2 . W3) into per-row energy ----
    auto LDA2 = [&](int kt, bf16x8* a) {
        #pragma unroll
        for (int mt = 0; mt < 2; ++mt)
            a[mt] = *reinterpret_cast<const bf16x8*>(
                &h1_lds[mt*32 + l31][kt*16 + (lhi << 3)]);
    };

    f32x16 acc[2][4];
    #pragma unroll
    for (int mt = 0; mt < 2; ++mt)
        #pragma unroll
        for (int nti = 0; nti < 4; ++nti)
            #pragma unroll
            for (int r = 0; r < 16; ++r) acc[mt][nti][r] = 0.0f;

    bf16x8 aC[2], aN[2];
    LDA2(0, aC);
    LDA2(1, aN);

    #pragma unroll 4
    for (int kt = 0; kt < KT2 - 2; kt += 2) {
        bf16x8 aP[2], bP[4];
        LDB2(kt + 2, bP);
        LDA2(kt + 2, aP);
        #pragma unroll
        for (int nti = 0; nti < 4; ++nti)
            #pragma unroll
            for (int mt = 0; mt < 2; ++mt)
                acc[mt][nti] = mfma32(aC[mt], bC[nti], acc[mt][nti]);
        bf16x8 aQ[2], bQ[4];
        LDB2(kt + 3, bQ);
        LDA2(kt + 3, aQ);
        #pragma unroll
        for (int nti = 0; nti < 4; ++nti)
            #pragma unroll
            for (int mt = 0; mt < 2; ++mt)
                acc[mt][nti] = mfma32(aN[mt], bN[nti], acc[mt][nti]);
        #pragma unroll
        for (int i = 0; i < 2; ++i) { aC[i] = aP[i]; aN[i] = aQ[i]; }
        #pragma unroll
        for (int i = 0; i < 4; ++i) { bC[i] = bP[i]; bN[i] = bQ[i]; }
    }
    // last two kt steps (62, 63): no prefetch
    #pragma unroll
    for (int nti = 0; nti < 4; ++nti)
        #pragma unroll
        for (int mt = 0; mt < 2; ++mt)
            acc[mt][nti] = mfma32(aC[mt], bC[nti], acc[mt][nti]);
    #pragma unroll
    for (int nti = 0; nti < 4; ++nti)
        #pragma unroll
        for (int mt = 0; mt < 2; ++mt)
            acc[mt][nti] = mfma32(aN[mt], bN[nti], acc[mt][nti]);

    // epilogue: silu + dot W3, reduce over 32 cols per lane-half
    float e_lane[32];
    #pragma unroll
    for (int i = 0; i < 32; ++i) e_lane[i] = 0.0f;

    #pragma unroll
    for (int nti = 0; nti < 4; ++nti) {
        int col = w*128 + nti*32 + l31;
        float bias = b2[col];
        float w3v  = w3[col];
        #pragma unroll
        for (int mt = 0; mt < 2; ++mt)
            #pragma unroll
            for (int r = 0; r < 16; ++r) {
                float s = silu_f(acc[mt][nti][r] + bias);
                e_lane[mt*16 + r] += s * w3v;
            }
    }

    // reduce across the 32 column-lanes (lane>>5 half stays intact)
    #pragma unroll
    for (int off = 1; off < 32; off <<= 1)
        #pragma unroll
        for (int i = 0; i < 32; ++i)
            e_lane[i] += __shfl_xor(e_lane[i], off, 64);

    if (l31 == 0) {
        #pragma unroll
        for (int mt = 0; mt < 2; ++mt)
            #pragma unroll
            for (int r = 0; r < 16; ++r) {
                int row = mt*32 + (r & 3) + 8*(r >> 2) + 4*lhi;
                e_red[w][row] = e_lane[mt*16 + r];
            }
    }
    __syncthreads();

    if (tid < BM) {
        float s = 0.0f;
        #pragma unroll
        for (int ww = 0; ww < 8; ++ww) s += e_red[ww][tid];
        node_e[row0 + tid] = s + b3[0];
    }
}

// ---------- deterministic segment sum over sorted batch ----------
__global__ void segsum(const float* __restrict__ node_e,
                       const int* __restrict__ batch,
                       float* __restrict__ out)
{
    int mol  = blockIdx.x;
    int lane = threadIdx.x;          // 64 threads

    int lo = 0, hi = NROWS;
    while (lo < hi) { int mid = (lo + hi) >> 1; if (batch[mid] < mol)     lo = mid + 1; else hi = mid; }
    int start = lo;
    lo = start; hi = NROWS;
    while (lo < hi) { int mid = (lo + hi) >> 1; if (batch[mid] < mol + 1) lo = mid + 1; else hi = mid; }
    int end = lo;

    float s = 0.0f;
    for (int i = start + lane; i < end; i += 64) s += node_e[i];
    #pragma unroll
    for (int off = 32; off; off >>= 1) s += __shfl_xor(s, off, 64);
    if (lane == 0) out[mol] = s;
}

// ---------- launch ----------
extern "C" void kernel_launch(void* const* d_in, const int* in_sizes, int n_in,
                              void* d_out, int out_size, void* d_ws, size_t ws_size,
                              hipStream_t stream) {
    const float* emb = (const float*)d_in[0];
    const float* W1  = (const float*)d_in[1];
    const float* b1  = (const float*)d_in[2];
    const float* W2  = (const float*)d_in[3];
    const float* b2  = (const float*)d_in[4];
    const float* W3  = (const float*)d_in[5];
    const float* b3  = (const float*)d_in[6];
    const int*   batch = (const int*)d_in[7];

    u16* w1f = (u16*)d_ws;                                        // 256 KB
    u16* w2f = (u16*)((char*)d_ws + (size_t)CIN * HDIM * 2);      // 2 MB
    float* node_e = (float*)((char*)d_ws + (size_t)CIN * HDIM * 2 + (size_t)HDIM * HDIM * 2);

    pack_w32<<<64,  256, 0, stream>>>(W1, w1f, CIN,  HDIM);
    pack_w32<<<512, 256, 0, stream>>>(W2, w2f, HDIM, HDIM);
    fused_mlp<<<NROWS / BM, 512, 0, stream>>>(emb, w1f, w2f, b1, b2, W3, b3, node_e);
    segsum<<<NMOL, 64, 0, stream>>>(node_e, batch, (float*)d_out);
}